// Round 4
// baseline (1537.522 us; speedup 1.0000x reference)
//
#include <hip/hip_runtime.h>

// ---------------- problem constants ----------------
#define NNODES 8192
#define NEDGES 262144
#define CCH    128          // sphere channels (C = EC = 128)
#define HCH    512          // hidden channels
#define GCOLS  6144         // 2*2560 (eq gates) + 2*512 (ne gates)
#define ROWS   204800       // N * M = 8192 * 25
#define XSPAD  136          // x LDS row stride (bf16 elems)
#define HGPAD  72           // hg LDS row stride

typedef __bf16 bf16_t;
typedef __bf16 bf16x8 __attribute__((ext_vector_type(8)));
typedef __bf16 bf16x4 __attribute__((ext_vector_type(4)));
typedef float  f32x4  __attribute__((ext_vector_type(4)));

__device__ __forceinline__ float siluf(float x) { return x / (1.f + __expf(-x)); }

// ---------------- workspace layout (bytes) ----------------
constexpr size_t OFF_CSUM  = 0;           // 8192*128 f32   = 4,194,304
constexpr size_t OFF_CNT   = 4194304;     // 8192 f32
constexpr size_t OFF_WRT   = 4227072;     // 8192*4 f32
constexpr size_t OFF_CBF   = 4358144;     // 8192*128 bf16
constexpr size_t OFF_WPT   = 6455296;     // 6144*128 bf16
constexpr size_t OFF_BPK   = 8028160;     // 6144 f32
constexpr size_t OFF_W1T   = 8052736;     // 4*512*128 bf16
constexpr size_t OFF_W2T   = 8577024;     // 4*128*512 bf16
constexpr size_t OFF_GATES = 9101312;     // chunk*6144 bf16 (adaptive)

// ---------------- kernel 1: scatter-add (fp32 t_ij) ----------------
__global__ __launch_bounds__(256) void scatter_kernel(
    const float* __restrict__ t_ij, const int* __restrict__ edge_index,
    float* __restrict__ csum, float* __restrict__ cnt)
{
  int idx = blockIdx.x * 256 + threadIdx.x;        // E*32 threads, 4 ch each
  int e = idx >> 5, sub = idx & 31;
  int dst = edge_index[NEDGES + e];                // edge_index[1][e], int32
  f32x4 t4 = *(const f32x4*)&t_ij[(size_t)e * CCH + sub * 4];
  float* base = csum + (size_t)dst * CCH + sub * 4;
  atomicAdd(base + 0, t4[0]);
  atomicAdd(base + 1, t4[1]);
  atomicAdd(base + 2, t4[2]);
  atomicAdd(base + 3, t4[3]);
  if (sub == 0) atomicAdd(cnt + dst, 1.0f);
}

// ---------------- kernel 2: mean + bf16 copy ----------------
__global__ __launch_bounds__(256) void mean_kernel(
    float* __restrict__ csum, const float* __restrict__ cnt, bf16_t* __restrict__ cbf)
{
  int idx = blockIdx.x * 256 + threadIdx.x;        // 8192*128 threads
  int n = idx >> 7;
  float v = csum[idx] / fmaxf(cnt[n], 1.f);
  csum[idx] = v;                                   // fp32 mean for router
  cbf[idx] = (bf16_t)v;
}

// ---------------- kernel 3: pack/transpose weights (fp32 -> bf16) ----------------
__global__ __launch_bounds__(256) void pack_kernel(
    const float* __restrict__ eq_gate_w, const float* __restrict__ ne_gate_w,
    const float* __restrict__ eq_gate_b, const float* __restrict__ ne_gate_b,
    const float* __restrict__ eq_w1, const float* __restrict__ ne_w1,
    const float* __restrict__ eq_w2, const float* __restrict__ ne_w2,
    bf16_t* __restrict__ WpackT, float* __restrict__ bpack,
    bf16_t* __restrict__ w1T, bf16_t* __restrict__ w2T)
{
  int idx = blockIdx.x * 256 + threadIdx.x;        // 1,316,864 total
  if (idx < 786432) {                              // WpackT[j][c] = Wpack[c][j]
    int j = idx >> 7, c = idx & 127;
    float v;
    if (j < 5120) { int e = j / 2560, h = j - e * 2560;
      v = eq_gate_w[(size_t)e * 327680 + (size_t)c * 2560 + h]; }
    else { int j2 = j - 5120; int e = j2 >> 9, h = j2 & 511;
      v = ne_gate_w[(size_t)e * 65536 + (size_t)c * 512 + h]; }
    WpackT[idx] = (bf16_t)v;
  } else if (idx < 792576) {                       // bpack (f32)
    int j = idx - 786432;
    float v;
    if (j < 5120) { int e = j / 2560; v = eq_gate_b[e * 2560 + (j - e * 2560)]; }
    else { int j2 = j - 5120; int e = j2 >> 9; v = ne_gate_b[e * 512 + (j2 & 511)]; }
    bpack[j] = v;
  } else if (idx < 1054720) {                      // w1T[e][h][c] = w1[e][c][h]
    int i = idx - 792576;
    int e = i >> 16, rest = i & 65535, h = rest >> 7, c = rest & 127;
    float v = (e < 2) ? eq_w1[(size_t)e * 65536 + (size_t)c * 512 + h]
                      : ne_w1[(size_t)(e - 2) * 65536 + (size_t)c * 512 + h];
    w1T[i] = (bf16_t)v;
  } else if (idx < 1316864) {                      // w2T[e][c][h] = w2[e][h][c]
    int i = idx - 1054720;
    int e = i >> 16, rest = i & 65535, c = rest >> 9, h = rest & 511;
    float v = (e < 2) ? eq_w2[(size_t)e * 65536 + (size_t)h * 128 + c]
                      : ne_w2[(size_t)(e - 2) * 65536 + (size_t)h * 128 + c];
    w2T[i] = (bf16_t)v;
  }
}

// ---------------- kernel 4: router (all fp32) ----------------
__global__ __launch_bounds__(128) void router_kernel(
    const float* __restrict__ c,
    const float* __restrict__ r_w1, const float* __restrict__ r_b1,
    const float* __restrict__ r_w2, const float* __restrict__ r_b2,
    float* __restrict__ wroute)
{
  __shared__ float cl[128];
  __shared__ float h1[128];
  __shared__ float lg[4];
  int n = blockIdx.x, tid = threadIdx.x;
  cl[tid] = c[(size_t)n * 128 + tid];
  __syncthreads();
  float a = 0.f;
  #pragma unroll 8
  for (int k = 0; k < 128; ++k) a += cl[k] * r_w1[k * 128 + tid];
  a += r_b1[tid];
  h1[tid] = siluf(a);
  __syncthreads();
  if (tid < 4) {
    float s = 0.f;
    for (int j = 0; j < 128; ++j) s += h1[j] * r_w2[j * 4 + tid];
    lg[tid] = s + r_b2[tid];
  }
  __syncthreads();
  if (tid == 0) {
    float m = fmaxf(fmaxf(lg[0], lg[1]), fmaxf(lg[2], lg[3]));
    float e0 = __expf(lg[0] - m), e1 = __expf(lg[1] - m);
    float e2 = __expf(lg[2] - m), e3 = __expf(lg[3] - m);
    float s = 1.f / (e0 + e1 + e2 + e3);
    f32x4 w = {e0 * s, e1 * s, e2 * s, e3 * s};
    *(f32x4*)&wroute[n * 4] = w;
  }
}

// ---------------- kernel 5: gate GEMM  gates[n][j] = silu(c@Wpack + b) ----------------
__global__ __launch_bounds__(256, 2) void gate_gemm_kernel(
    const bf16_t* __restrict__ WpackT, const bf16_t* __restrict__ cbf,
    const float* __restrict__ bpack, bf16_t* __restrict__ gates, int n0)
{
  __shared__ bf16_t gt[128 * XSPAD];
  int jt = blockIdx.x, nt = blockIdx.y;
  int tid = threadIdx.x;
  int wave = tid >> 6, lane = tid & 63;
  int wr = wave >> 1, wc = wave & 1;
  int l15 = lane & 15, quad = lane >> 4;

  f32x4 acc[4][4];
  #pragma unroll
  for (int i = 0; i < 4; ++i)
    #pragma unroll
    for (int j = 0; j < 4; ++j) acc[i][j] = {0.f, 0.f, 0.f, 0.f};

  const bf16_t* abase = WpackT + ((size_t)jt * 128 + wr * 64 + l15) * 128 + quad * 8;
  const bf16_t* bbase = cbf + ((size_t)(n0 + nt * 128) + wc * 64 + l15) * 128 + quad * 8;
  #pragma unroll
  for (int ks = 0; ks < 4; ++ks) {
    bf16x8 af[4], bfr[4];
    #pragma unroll
    for (int tr = 0; tr < 4; ++tr) af[tr] = *(const bf16x8*)(abase + (size_t)tr * 16 * 128 + ks * 32);
    #pragma unroll
    for (int tc = 0; tc < 4; ++tc) bfr[tc] = *(const bf16x8*)(bbase + (size_t)tc * 16 * 128 + ks * 32);
    #pragma unroll
    for (int tr = 0; tr < 4; ++tr)
      #pragma unroll
      for (int tc = 0; tc < 4; ++tc)
        acc[tr][tc] = __builtin_amdgcn_mfma_f32_16x16x32_bf16(af[tr], bfr[tc], acc[tr][tc], 0, 0, 0);
  }
  #pragma unroll
  for (int tr = 0; tr < 4; ++tr) {
    int j0 = wr * 64 + tr * 16 + quad * 4;
    f32x4 bb = *(const f32x4*)&bpack[jt * 128 + j0];
    #pragma unroll
    for (int tc = 0; tc < 4; ++tc) {
      int nl = wc * 64 + tc * 16 + l15;
      f32x4 v = acc[tr][tc];
      bf16x4 gv;
      #pragma unroll
      for (int q = 0; q < 4; ++q) gv[q] = (bf16_t)siluf(v[q] + bb[q]);
      *(bf16x4*)&gt[nl * XSPAD + j0] = gv;
    }
  }
  __syncthreads();
  #pragma unroll
  for (int it = 0; it < 8; ++it) {
    int idx = it * 2048 + tid * 8;
    int lr = idx >> 7, col = idx & 127;
    *(bf16x8*)&gates[((size_t)nt * 128 + lr) * GCOLS + jt * 128 + col] =
        *(const bf16x8*)&gt[lr * XSPAD + col];
  }
}

// ---------------- kernel 6: fused experts ----------------
// per block: 128 rows of (n,m) space within node-chunk starting at n0.
// GEMM1 (operand-swapped): D1[h, r] = w1T x.  gate -> hg LDS [r][h] bf16.
// GEMM2: D2[c, r] += w2T hg.  Epilogue adds ne b2 terms, stores fp32.
__global__ __launch_bounds__(256, 2) void fused_experts_kernel(
    const float* __restrict__ x,       // [204800][128] fp32
    const bf16_t* __restrict__ w1T,    // [4][512][128]
    const bf16_t* __restrict__ w2T,    // [4][128][512]
    const bf16_t* __restrict__ gates,  // [chunk][6144] (node n at row n-n0)
    const float* __restrict__ wroute,  // [8192][4]
    const float* __restrict__ ne_b1,   // [2][512] fp32
    const float* __restrict__ ne_b2,   // [2][128] fp32
    float* __restrict__ out,           // [204800][128] fp32
    int n0)
{
  __shared__ bf16_t xs[128 * XSPAD];
  __shared__ bf16_t hg[128 * HGPAD];
  __shared__ float rwsh[128 * 4];
  __shared__ int rn[128];              // node-local (n - n0)
  __shared__ int rl[128];

  const int tid = threadIdx.x;
  const int r0 = n0 * 25 + blockIdx.x * 128;

  // stage x fp32 -> bf16 LDS
  #pragma unroll
  for (int it = 0; it < 8; ++it) {
    int idx = it * 2048 + tid * 8;
    int lr = idx >> 7, col = idx & 127;
    f32x4 a = *(const f32x4*)&x[(size_t)r0 * 128 + idx];
    f32x4 b = *(const f32x4*)&x[(size_t)r0 * 128 + idx + 4];
    bf16x8 v;
    #pragma unroll
    for (int q = 0; q < 4; ++q) { v[q] = (bf16_t)a[q]; v[4 + q] = (bf16_t)b[q]; }
    *(bf16x8*)&xs[lr * XSPAD + col] = v;
  }
  if (tid < 128) {
    int r = r0 + tid;
    int n = r / 25;
    int m = r - n * 25;
    rn[tid] = n - n0;
    rl[tid] = (m == 0) ? 0 : (m < 4) ? 1 : (m < 9) ? 2 : (m < 16) ? 3 : 4;
    *(f32x4*)&rwsh[tid * 4] = *(const f32x4*)&wroute[n * 4];
  }
  __syncthreads();

  const int wave = tid >> 6, lane = tid & 63;
  const int wr = wave >> 1, wc = wave & 1;
  const int l15 = lane & 15, quad = lane >> 4;

  f32x4 oacc[4][4];
  #pragma unroll
  for (int i = 0; i < 4; ++i)
    #pragma unroll
    for (int j = 0; j < 4; ++j) oacc[i][j] = {0.f, 0.f, 0.f, 0.f};

  #pragma unroll 1
  for (int e = 0; e < 4; ++e) {
    const bool is_eq = (e < 2);
    #pragma unroll 1
    for (int hc = 0; hc < 8; ++hc) {
      // ---- GEMM1: hacc[h(2x16)][r(4x16)], K=128 ----
      f32x4 hacc[2][4];
      #pragma unroll
      for (int i = 0; i < 2; ++i)
        #pragma unroll
        for (int j = 0; j < 4; ++j) hacc[i][j] = {0.f, 0.f, 0.f, 0.f};
      const bf16_t* a1 = w1T + ((size_t)e * 512 + hc * 64 + wr * 32 + l15) * 128 + quad * 8;
      #pragma unroll
      for (int ks = 0; ks < 4; ++ks) {
        bf16x8 af[2], bfr[4];
        af[0] = *(const bf16x8*)(a1 + ks * 32);
        af[1] = *(const bf16x8*)(a1 + 16 * 128 + ks * 32);
        #pragma unroll
        for (int tc = 0; tc < 4; ++tc)
          bfr[tc] = *(const bf16x8*)&xs[(wc * 64 + tc * 16 + l15) * XSPAD + ks * 32 + quad * 8];
        #pragma unroll
        for (int tr = 0; tr < 2; ++tr)
          #pragma unroll
          for (int tc = 0; tc < 4; ++tc)
            hacc[tr][tc] = __builtin_amdgcn_mfma_f32_16x16x32_bf16(af[tr], bfr[tc], hacc[tr][tc], 0, 0, 0);
      }
      __syncthreads();   // previous GEMM2 reads of hg complete
      // ---- gating + hg write ----
      #pragma unroll
      for (int tc = 0; tc < 4; ++tc) {
        int rloc = wc * 64 + tc * 16 + l15;
        int n = rn[rloc], l = rl[rloc];
        float wre = rwsh[rloc * 4 + e];
        #pragma unroll
        for (int tr = 0; tr < 2; ++tr) {
          int hl = wr * 32 + tr * 16 + quad * 4;     // h within chunk [0,64)
          int hgl = hc * 64 + hl;                    // h within expert [0,512)
          f32x4 v = hacc[tr][tc];
          bf16x4 gv;
          if (is_eq) {
            gv = *(const bf16x4*)&gates[(size_t)n * GCOLS + e * 2560 + l * 512 + hgl];
            if (l == 0) {
              #pragma unroll
              for (int q = 0; q < 4; ++q) v[q] = siluf(v[q]);
            }
          } else {
            gv = *(const bf16x4*)&gates[(size_t)n * GCOLS + 5120 + (e - 2) * 512 + hgl];
            f32x4 b1 = *(const f32x4*)&ne_b1[(e - 2) * 512 + hgl];
            #pragma unroll
            for (int q = 0; q < 4; ++q) v[q] = siluf(v[q] + b1[q]);
          }
          bf16x4 hv;
          #pragma unroll
          for (int q = 0; q < 4; ++q) hv[q] = (bf16_t)(v[q] * (float)gv[q] * wre);
          *(bf16x4*)&hg[rloc * HGPAD + hl] = hv;
        }
      }
      __syncthreads();
      // ---- GEMM2: oacc[c][r] += w2T(chunk) * hg, K=64 ----
      const bf16_t* a2 = w2T + ((size_t)e * 128 + wr * 64 + l15) * 512 + hc * 64 + quad * 8;
      #pragma unroll
      for (int ks = 0; ks < 2; ++ks) {
        bf16x8 af[4], bfr[4];
        #pragma unroll
        for (int tr = 0; tr < 4; ++tr)
          af[tr] = *(const bf16x8*)(a2 + (size_t)tr * 16 * 512 + ks * 32);
        #pragma unroll
        for (int tc = 0; tc < 4; ++tc)
          bfr[tc] = *(const bf16x8*)&hg[(wc * 64 + tc * 16 + l15) * HGPAD + ks * 32 + quad * 8];
        #pragma unroll
        for (int tr = 0; tr < 4; ++tr)
          #pragma unroll
          for (int tc = 0; tc < 4; ++tc)
            oacc[tr][tc] = __builtin_amdgcn_mfma_f32_16x16x32_bf16(af[tr], bfr[tc], oacc[tr][tc], 0, 0, 0);
      }
    }
  }
  // ---- epilogue: out[r][c] = oacc + w_ne*b2 terms (fp32 store) ----
  #pragma unroll
  for (int tc = 0; tc < 4; ++tc) {
    int rloc = wc * 64 + tc * 16 + l15;
    size_t rg = (size_t)(r0 + rloc);
    float wn0 = rwsh[rloc * 4 + 2], wn1 = rwsh[rloc * 4 + 3];
    #pragma unroll
    for (int tr = 0; tr < 4; ++tr) {
      int c0 = wr * 64 + tr * 16 + quad * 4;
      f32x4 v = oacc[tr][tc];
      f32x4 b20 = *(const f32x4*)&ne_b2[c0];
      f32x4 b21 = *(const f32x4*)&ne_b2[128 + c0];
      f32x4 ov;
      #pragma unroll
      for (int q = 0; q < 4; ++q)
        ov[q] = v[q] + wn0 * b20[q] + wn1 * b21[q];
      *(f32x4*)&out[rg * 128 + c0] = ov;
    }
  }
}

// ---------------- launch ----------------
extern "C" void kernel_launch(void* const* d_in, const int* in_sizes, int n_in,
                              void* d_out, int out_size, void* d_ws, size_t ws_size,
                              hipStream_t stream)
{
  const float* x_emb     = (const float*)d_in[0];
  const float* t_ij      = (const float*)d_in[1];
  const int*   edge_index= (const int*)d_in[2];
  const float* eq_w1     = (const float*)d_in[3];
  const float* eq_gate_w = (const float*)d_in[4];
  const float* eq_gate_b = (const float*)d_in[5];
  const float* eq_w2     = (const float*)d_in[6];
  const float* ne_w1     = (const float*)d_in[7];
  const float* ne_b1     = (const float*)d_in[8];
  const float* ne_gate_w = (const float*)d_in[9];
  const float* ne_gate_b = (const float*)d_in[10];
  const float* ne_w2     = (const float*)d_in[11];
  const float* ne_b2     = (const float*)d_in[12];
  const float* r_w1      = (const float*)d_in[13];
  const float* r_b1      = (const float*)d_in[14];
  const float* r_w2      = (const float*)d_in[15];
  const float* r_b2      = (const float*)d_in[16];
  float* out = (float*)d_out;

  char* ws = (char*)d_ws;
  float*  csum   = (float*)(ws + OFF_CSUM);
  float*  cnt    = (float*)(ws + OFF_CNT);
  float*  wroute = (float*)(ws + OFF_WRT);
  bf16_t* cbf    = (bf16_t*)(ws + OFF_CBF);
  bf16_t* WpackT = (bf16_t*)(ws + OFF_WPT);
  float*  bpack  = (float*)(ws + OFF_BPK);
  bf16_t* w1T    = (bf16_t*)(ws + OFF_W1T);
  bf16_t* w2T    = (bf16_t*)(ws + OFF_W2T);
  bf16_t* gates  = (bf16_t*)(ws + OFF_GATES);

  // Adaptive node-chunking for the gates buffer (ws_size constant across calls).
  size_t avail = (ws_size > OFF_GATES) ? ws_size - OFF_GATES : 0;
  int chunk = 128;
  for (int c = NNODES; c >= 128; c >>= 1) {
    if ((size_t)c * GCOLS * sizeof(bf16_t) <= avail) { chunk = c; break; }
  }

  hipMemsetAsync(ws, 0, OFF_WRT, stream);   // zero csum + cnt

  scatter_kernel<<<NEDGES * 32 / 256, 256, 0, stream>>>(t_ij, edge_index, csum, cnt);
  mean_kernel<<<NNODES * CCH / 256, 256, 0, stream>>>(csum, cnt, cbf);
  pack_kernel<<<5144, 256, 0, stream>>>(eq_gate_w, ne_gate_w, eq_gate_b, ne_gate_b,
                                        eq_w1, ne_w1, eq_w2, ne_w2,
                                        WpackT, bpack, w1T, w2T);
  router_kernel<<<NNODES, 128, 0, stream>>>(csum, r_w1, r_b1, r_w2, r_b2, wroute);

  for (int n0 = 0; n0 < NNODES; n0 += chunk) {
    gate_gemm_kernel<<<dim3(GCOLS / 128, chunk / 128), 256, 0, stream>>>(
        WpackT, cbf, bpack, gates, n0);
    fused_experts_kernel<<<chunk * 25 / 128, 256, 0, stream>>>(
        x_emb, w1T, w2T, gates, wroute, ne_b1, ne_b2, out, n0);
  }
}